// Round 12
// baseline (133.158 us; speedup 1.0000x reference)
//
#include <hip/hip_runtime.h>
#include <stdint.h>

#define KCAPS 10
#define OC    16
#define IC    256
#define HWSZ  36
#define PRIM  72
#define PD    8
#define EDIM  16
#define BMAX  2048

typedef short bf16x8 __attribute__((ext_vector_type(8)));
typedef float f32x4  __attribute__((ext_vector_type(4)));

// persistent prepped data (recomputed every launch -> deterministic)
__device__ unsigned short g_whi[KCAPS * OC * IC];
__device__ unsigned short g_wlo[KCAPS * OC * IC];
__device__ float4         g_wtsT4[KCAPS * PD * 4 * PRIM];     // [k][(d*4+e4)][p]
__device__ __align__(16) unsigned short g_xhi[(size_t)BMAX * 36 * 264];  // [b][hw][264] bf16 hi
__device__ __align__(16) unsigned short g_xlo[(size_t)BMAX * 36 * 264];  // lo plane
__device__ float          g_caps_fallback[(size_t)BMAX * 160 * HWSZ];

// kernel A LDS: xsh bf16[36][264] (19008 B) | xsl bf16[36][264] (19008 B) = 38016 B
#define SMEM_A 38016
// kernel B LDS: u_t f32[16][724] | b_s[720] | c_s[720] | v_s[160] | scale_s[10]
#define SMEM_B (13194 * 4)

__device__ __forceinline__ void bf_split(float v, unsigned short& hb, unsigned short& lb) {
    __bf16 h = (__bf16)v;
    hb = __builtin_bit_cast(unsigned short, h);
    __bf16 l = (__bf16)(v - (float)h);
    lb = __builtin_bit_cast(unsigned short, l);
}

__device__ __forceinline__ f32x4 mfma16(bf16x8 a, bf16x8 b, f32x4 c) {
    return __builtin_amdgcn_mfma_f32_16x16x32_bf16(a, b, c, 0, 0, 0);
}

__global__ __launch_bounds__(256)
void prep_kernel(const float* __restrict__ w, const float* __restrict__ wts) {
    int i = blockIdx.x * 256 + threadIdx.x;
    if (i < KCAPS * OC * IC) {                 // 40960
        unsigned short hb, lb;
        bf_split(w[i], hb, lb);
        g_whi[i] = hb;
        g_wlo[i] = lb;
    }
    if (i < KCAPS * PD * 4 * PRIM) {           // 23040 float4 tasks
        int p = i % PRIM;
        int r = i / PRIM;
        int e4 = r & 3;
        int d  = (r >> 2) & 7;
        int k  = r >> 5;
        g_wtsT4[i] = *(const float4*)(wts + (size_t)(((k * PRIM + p) * PD + d) * EDIM + e4 * 4));
    }
}

// ---- kernel T: x [b][c][hw] f32 -> padded transposed bf16 hi/lo planes [b][hw][264]
__global__ __launch_bounds__(256)
void xpose_kernel(const float* __restrict__ x) {
    __shared__ float xf[IC * HWSZ];            // 36864 B
    const int t = threadIdx.x;
    const int b = blockIdx.x;
    const float4* x4 = (const float4*)(x + (size_t)b * (IC * HWSZ));
    float4* l4 = (float4*)xf;
    for (int j = t; j < (IC * HWSZ) / 4; j += 256) l4[j] = x4[j];   // coalesced, linear
    __syncthreads();
    uint32_t* hi = (uint32_t*)(g_xhi + (size_t)b * (36 * 264));
    uint32_t* lo = (uint32_t*)(g_xlo + (size_t)b * (36 * 264));
    for (int task = t; task < 36 * 128; task += 256) {   // hw x c-pair
        int hw = task >> 7;
        int cp = task & 127;
        float a = xf[(2 * cp) * HWSZ + hw];
        float c = xf[(2 * cp + 1) * HWSZ + hw];
        unsigned short ha, la, hb, lb;
        bf_split(a, ha, la);
        bf_split(c, hb, lb);
        hi[hw * 132 + cp] = (uint32_t)ha | ((uint32_t)hb << 16);   // coalesced over cp
        lo[hw * 132 + cp] = (uint32_t)la | ((uint32_t)lb << 16);
    }
}

// ---- kernel A: per-batch-element conv GEMM (bf16 3-pass), caps -> global f32.
//      n-tiles rebased at hw {0,16,20} so all A-fragment rows are in-bounds (no slack).
__global__ __launch_bounds__(256, 2)
void gemm_caps(const float* __restrict__ conv_b, float* __restrict__ caps_g) {
    extern __shared__ char smem[];
    const short* xshS = (const short*)smem;              // [36][264]
    const short* xslS = xshS + 36 * 264;                 // [36][264]

    const int t  = threadIdx.x;
    const int bb = blockIdx.x;
    const int wv = t >> 6;            // 4 waves; wave wv -> m-tiles {wv, wv+4[, wv+8]}
    const int ln = t & 63;
    const int row = ln & 15;
    const int g   = ln >> 4;
    const int nm  = (wv < 2) ? 3 : 2;

    // stage both planes: 2376 coalesced dwordx4, linear LDS copy (no transpose math)
    {
        const float4* gh = (const float4*)(g_xhi + (size_t)bb * (36 * 264));
        const float4* gl = (const float4*)(g_xlo + (size_t)bb * (36 * 264));
        float4* ls = (float4*)smem;
        for (int j = t; j < 2376; j += 256)
            ls[j] = (j < 1188) ? gh[j] : gl[j - 1188];
    }
    __syncthreads();

    const int hwbase[3] = {0, 16, 20};

    f32x4 acc[3][3] = {};
    for (int kt = 0; kt < 8; ++kt) {
        bf16x8 bh[3], bl[3];
        #pragma unroll
        for (int mi = 0; mi < 3; ++mi) {
            if (mi < nm) {
                int woff = ((wv + 4 * mi) * 16 + row) * 256 + kt * 32 + g * 8;
                bh[mi] = *(const bf16x8*)(g_whi + woff);
                bl[mi] = *(const bf16x8*)(g_wlo + woff);
            }
        }
        bf16x8 ah[3], al[3];
        #pragma unroll
        for (int nt = 0; nt < 3; ++nt) {
            int o2 = (hwbase[nt] + row) * 264 + kt * 32 + g * 8;
            ah[nt] = *(const bf16x8*)(xshS + o2);
            al[nt] = *(const bf16x8*)(xslS + o2);
        }
        #pragma unroll
        for (int mi = 0; mi < 3; ++mi) {
            if (mi < nm) {
                #pragma unroll
                for (int nt = 0; nt < 3; ++nt) {
                    acc[mi][nt] = mfma16(ah[nt], bh[mi], acc[mi][nt]);
                    acc[mi][nt] = mfma16(al[nt], bh[mi], acc[mi][nt]);
                    acc[mi][nt] = mfma16(ah[nt], bl[mi], acc[mi][nt]);
                }
            }
        }
    }

    // C-write (+bias): D-row hw = hwbase[nt] + g*4 + r; tile2 writes only g==3 (hw 32-35)
    float* cg = caps_g + (size_t)bb * (160 * HWSZ);
    #pragma unroll
    for (int mi = 0; mi < 3; ++mi) {
        if (mi < nm) {
            int m = (wv + 4 * mi) * 16 + row;
            float bias = conv_b[m];
            #pragma unroll
            for (int nt = 0; nt < 3; ++nt) {
                int hw0 = hwbase[nt] + g * 4;
                if (nt < 2 || g == 3) {
                    float4 o;
                    o.x = acc[mi][nt][0] + bias;
                    o.y = acc[mi][nt][1] + bias;
                    o.z = acc[mi][nt][2] + bias;
                    o.w = acc[mi][nt][3] + bias;
                    *(float4*)(cg + m * HWSZ + hw0) = o;
                }
            }
        }
    }
}

// ---- kernel B: u-transform + dynamic routing per batch element (R11-proven)
__global__ __launch_bounds__(256, 2)
void route_kernel(const float* __restrict__ caps_g, float* __restrict__ out) {
    extern __shared__ char smem[];
    float* u_t     = (float*)smem;            // [16][724]
    float* b_s     = u_t + 16 * 724;          // [720]
    float* c_s     = b_s + 720;               // [720]
    float* v_s     = c_s + 720;               // [160]
    float* scale_s = v_s + 160;               // [10]

    const int t  = threadIdx.x;
    const int bb = blockIdx.x;

    {
        const float4* cg4 = (const float4*)(caps_g + (size_t)bb * (160 * HWSZ));
        for (int task = t; task < KCAPS * PRIM; task += 256) {
            int k = task / PRIM;
            int p = task - k * PRIM;
            float4 c0 = cg4[task * 2];
            float4 c1 = cg4[task * 2 + 1];
            float pv[PD] = {c0.x, c0.y, c0.z, c0.w, c1.x, c1.y, c1.z, c1.w};
            const float4* wb = g_wtsT4 + k * (PD * 4 * PRIM) + p;
            float au[EDIM] = {};
            #pragma unroll
            for (int d = 0; d < PD; ++d) {
                #pragma unroll
                for (int e4 = 0; e4 < 4; ++e4) {
                    float4 w4 = wb[(d * 4 + e4) * PRIM];
                    au[e4 * 4 + 0] = fmaf(pv[d], w4.x, au[e4 * 4 + 0]);
                    au[e4 * 4 + 1] = fmaf(pv[d], w4.y, au[e4 * 4 + 1]);
                    au[e4 * 4 + 2] = fmaf(pv[d], w4.z, au[e4 * 4 + 2]);
                    au[e4 * 4 + 3] = fmaf(pv[d], w4.w, au[e4 * 4 + 3]);
                }
            }
            #pragma unroll
            for (int e = 0; e < EDIM; ++e) u_t[e * 724 + task] = au[e];
        }
    }
    for (int i = t; i < KCAPS * PRIM; i += 256) b_s[i] = 0.f;
    __syncthreads();

    for (int it = 0; it < 3; ++it) {
        if (t < PRIM) {
            float bv[KCAPS];
            float m = -1e30f;
            #pragma unroll
            for (int k2 = 0; k2 < KCAPS; ++k2) { bv[k2] = b_s[k2 * PRIM + t]; m = fmaxf(m, bv[k2]); }
            float sum = 0.f;
            #pragma unroll
            for (int k2 = 0; k2 < KCAPS; ++k2) { bv[k2] = __expf(bv[k2] - m); sum += bv[k2]; }
            float inv = 1.f / sum;
            #pragma unroll
            for (int k2 = 0; k2 < KCAPS; ++k2) c_s[k2 * PRIM + t] = bv[k2] * inv;
        }
        __syncthreads();

        if (t < KCAPS * EDIM) {
            int k = t >> 4, e = t & 15;
            float s = 0.f;
            const float* ur = u_t + e * 724 + k * PRIM;
            const float* cr = c_s + k * PRIM;
            for (int p = 0; p < PRIM; ++p) s = fmaf(cr[p], ur[p], s);
            v_s[t] = s;
        }
        __syncthreads();

        if (t < KCAPS) {
            float sq = 0.f;
            #pragma unroll
            for (int e = 0; e < EDIM; ++e) { float sv = v_s[t * EDIM + e]; sq = fmaf(sv, sv, sq); }
            scale_s[t] = (sq / (1.f + sq)) * rsqrtf(sq + 1e-8f);
        }
        __syncthreads();

        if (t < KCAPS * EDIM) v_s[t] *= scale_s[t >> 4];
        __syncthreads();

        if (it < 2) {
            for (int task = t; task < KCAPS * PRIM; task += 256) {
                int k = task / PRIM;
                float dot = 0.f;
                const float* vr = v_s + k * EDIM;
                #pragma unroll
                for (int e = 0; e < EDIM; ++e) dot = fmaf(u_t[e * 724 + task], vr[e], dot);
                b_s[task] += dot;
            }
            __syncthreads();
        }
    }

    if (t < KCAPS * EDIM) out[(size_t)bb * (KCAPS * EDIM) + t] = v_s[t];
}

extern "C" void kernel_launch(void* const* d_in, const int* in_sizes, int n_in,
                              void* d_out, int out_size, void* d_ws, size_t ws_size,
                              hipStream_t stream) {
    const float* x  = (const float*)d_in[0];
    const float* cw = (const float*)d_in[1];
    const float* cb = (const float*)d_in[2];
    const float* wt = (const float*)d_in[3];
    float* out = (float*)d_out;
    const int B = in_sizes[0] / (IC * HWSZ);   // 2048

    size_t capsNeed = (size_t)B * 160 * HWSZ * sizeof(float);   // 47.2 MB
    float* caps_g = nullptr;
    if (d_ws != nullptr && ws_size >= capsNeed) {
        caps_g = (float*)d_ws;
    } else {
        void* sym = nullptr;
        hipGetSymbolAddress(&sym, HIP_SYMBOL(g_caps_fallback));
        caps_g = (float*)sym;
    }

    hipLaunchKernelGGL(prep_kernel, dim3(160), dim3(256), 0, stream, cw, wt);
    hipLaunchKernelGGL(xpose_kernel, dim3(B), dim3(256), 0, stream, x);

    hipFuncSetAttribute(reinterpret_cast<const void*>(&gemm_caps),
                        hipFuncAttributeMaxDynamicSharedMemorySize, SMEM_A);
    hipLaunchKernelGGL(gemm_caps, dim3(B), dim3(256), SMEM_A, stream, cb, caps_g);

    hipFuncSetAttribute(reinterpret_cast<const void*>(&route_kernel),
                        hipFuncAttributeMaxDynamicSharedMemorySize, SMEM_B);
    hipLaunchKernelGGL(route_kernel, dim3(B), dim3(256), SMEM_B, stream, caps_g, out);
}